// Round 20
// baseline (295.842 us; speedup 1.0000x reference)
//
#include <hip/hip_runtime.h>

typedef _Float16 f16;
typedef _Float16 f16x8 __attribute__((ext_vector_type(8)));
typedef _Float16 f16x4 __attribute__((ext_vector_type(4)));
typedef _Float16 f16x2 __attribute__((ext_vector_type(2)));
typedef __fp16 fp16x2 __attribute__((ext_vector_type(2)));
typedef float f32x4 __attribute__((ext_vector_type(4)));

#define SEQ   2048
#define DM    1024
#define DKH   64
#define MTOT  4096  // B*S

__device__ __forceinline__ f32x4 mfma16(f16x8 a, f16x8 b, f32x4 c) {
  return __builtin_amdgcn_mfma_f32_16x16x32_f16(a, b, c, 0, 0, 0);
}

__device__ __forceinline__ f16x2 cvt_pk(float a, float b) {
  fp16x2 r = __builtin_amdgcn_cvt_pkrtz(a, b);
  return __builtin_bit_cast(f16x2, r);
}

// async global->LDS, 16B per lane; LDS dest = uniform base + lane*16 (HW rule)
__device__ __forceinline__ void gload16(const f16* g, f16* l) {
  __builtin_amdgcn_global_load_lds(
      (const __attribute__((address_space(1))) void*)g,
      (__attribute__((address_space(3))) void*)l, 16, 0, 0);
}

// ------- merged prep: blocks 0..4095 cast weights, 4096..8191 LayerNorm -----
__global__ __launch_bounds__(256) void prep_kernel(const float* __restrict__ x,
                                                   const float* __restrict__ w_q,
                                                   const float* __restrict__ w_k,
                                                   const float* __restrict__ w_v,
                                                   const float* __restrict__ w_o,
                                                   const float* __restrict__ gamma,
                                                   const float* __restrict__ beta,
                                                   f16* __restrict__ wout,
                                                   f16* __restrict__ xn) {
  const int t = threadIdx.x;
  if (blockIdx.x < 4096) {
    const int sel = blockIdx.x >> 10;
    const float* src = sel == 0 ? w_q : sel == 1 ? w_k : sel == 2 ? w_v : w_o;
    const int i = ((blockIdx.x & 1023) * 256 + t) * 4;
    float4 v = *reinterpret_cast<const float4*>(src + i);
    f16x4 o;
    o[0] = (f16)v.x; o[1] = (f16)v.y; o[2] = (f16)v.z; o[3] = (f16)v.w;
    *reinterpret_cast<f16x4*>(wout + (size_t)sel * 1048576 + i) = o;
    return;
  }
  const int row = blockIdx.x - 4096;
  const float* xr = x + (size_t)row * DM;
  float v[4], s = 0.f, s2 = 0.f;
#pragma unroll
  for (int i = 0; i < 4; ++i) {
    v[i] = xr[t + i * 256];
    s += v[i];
    s2 += v[i] * v[i];
  }
#pragma unroll
  for (int o = 32; o > 0; o >>= 1) {
    s  += __shfl_down(s, o);
    s2 += __shfl_down(s2, o);
  }
  __shared__ float ps[4], ps2[4], mu_s, rs_s;
  if ((t & 63) == 0) { ps[t >> 6] = s; ps2[t >> 6] = s2; }
  __syncthreads();
  if (t == 0) {
    float a = ps[0] + ps[1] + ps[2] + ps[3];
    float b = ps2[0] + ps2[1] + ps2[2] + ps2[3];
    float mu = a * (1.f / DM);
    float var = b * (1.f / DM) - mu * mu;
    mu_s = mu;
    rs_s = rsqrtf(var + 1e-5f);
  }
  __syncthreads();
  const float mu = mu_s, rs = rs_s;
#pragma unroll
  for (int i = 0; i < 4; ++i) {
    int d = t + i * 256;
    xn[(size_t)row * DM + d] = (f16)(((v[i] - mu) * rs) * gamma[d] + beta[d]);
  }
}

// ---------------- fused QKV GEMM: C[M,3072] = xn @ Wqkv^T --------------------
// 128x64 tile + 2-phase dbuf (r16-proven schedule). 1D grid 1536 with
// 8x8 PATCH-MAJOR XCD decomposition (r19-proven): per-XCD working set ~3 MB
// (L2-fit) -> staging loads are L2 hits.
__global__ __launch_bounds__(256) void gemm_qkv(const f16* __restrict__ A,
                                                const f16* __restrict__ Wqkv,
                                                f16* __restrict__ qb,
                                                f16* __restrict__ kb,
                                                f16* __restrict__ vtb) {
  __shared__ f16 sA[2][128][64];  // 32 KB
  __shared__ f16 sB[2][64][64];   // 16 KB
  const int t = threadIdx.x, l = t & 63, w = t >> 6;
  const int wr = w >> 1, wc = w & 1, lg = l >> 4, lm = l & 15;
  // patch-major remap: XCD c = orig%8 gets u = c*192 + orig/8; 8x8 patches
  const int orig = blockIdx.x;
  const int u = (orig & 7) * 192 + (orig >> 3);
  const int g = u >> 6, wj = u & 63;
  const int by = (g / 6) * 8 + (wj >> 3);
  const int bxn = (g % 6) * 8 + (wj & 7);
  const int m0 = by * 128, n0 = bxn * 64;
  const int crow = l >> 3;                 // lane's row within 8-row chunk
  const int scol = ((l & 7) ^ crow) << 3;  // pre-swizzled source col (f16)
  const int rsw  = (lm & 7) << 3;          // read-side swizzle XOR (f16)

  f32x4 acc[4][2] = {};

  auto stage = [&](int buf, int k0) {
#pragma unroll
    for (int cc = 0; cc < 4; ++cc) {
      const int c = w + cc * 4;            // chunk 0..15 (8 rows each)
      gload16(A + (size_t)(m0 + c * 8 + crow) * DM + k0 + scol, &sA[buf][c * 8][0]);
    }
#pragma unroll
    for (int cc = 0; cc < 2; ++cc) {
      const int c = w + cc * 4;            // chunk 0..7
      gload16(Wqkv + (size_t)(n0 + c * 8 + crow) * DM + k0 + scol, &sB[buf][c * 8][0]);
    }
  };

  stage(0, 0);
  __syncthreads();
  int cur = 0;

  for (int it = 0; it < DM / 64; ++it) {
    if (it < DM / 64 - 1) stage(cur ^ 1, (it + 1) * 64);
#pragma unroll
    for (int kk = 0; kk < 2; ++kk) {
      f16x8 af[4], bf[2];
#pragma unroll
      for (int i = 0; i < 4; ++i)
        af[i] = *(const f16x8*)&sA[cur][wr * 64 + i * 16 + lm][(kk * 32 + lg * 8) ^ rsw];
#pragma unroll
      for (int i = 0; i < 2; ++i)
        bf[i] = *(const f16x8*)&sB[cur][wc * 32 + i * 16 + lm][(kk * 32 + lg * 8) ^ rsw];
      __builtin_amdgcn_s_setprio(1);
#pragma unroll
      for (int mi = 0; mi < 4; ++mi)
#pragma unroll
        for (int ni = 0; ni < 2; ++ni)
          acc[mi][ni] = mfma16(af[mi], bf[ni], acc[mi][ni]);
      __builtin_amdgcn_s_setprio(0);
    }
    __syncthreads();
    cur ^= 1;
  }

  const int sel = bxn >> 4;  // 0:Q 1:K 2:V  (16 n-blocks per matrix)
  if (sel < 2) {
    f16* outp = sel == 0 ? qb : kb;
    const int nloc = n0 - sel * 1024;
#pragma unroll
    for (int mi = 0; mi < 4; ++mi) {
      const int rowb = m0 + wr * 64 + mi * 16 + lg * 4;
#pragma unroll
      for (int ni = 0; ni < 2; ++ni) {
        const int col = nloc + wc * 32 + ni * 16 + lm;
#pragma unroll
        for (int r = 0; r < 4; ++r)
          outp[(size_t)(rowb + r) * DM + col] = (f16)acc[mi][ni][r];
      }
    }
  } else {
    // V: write transposed. global row m = b*2048+s ; col = h*64+d
    // Vt idx = (b*1024 + col)*SEQ + s ; r (=s) contiguous -> packed 8B store
#pragma unroll
    for (int mi = 0; mi < 4; ++mi) {
      const int rowb = m0 + wr * 64 + mi * 16 + lg * 4;
      const int b = rowb >> 11, s = rowb & 2047;
#pragma unroll
      for (int ni = 0; ni < 2; ++ni) {
        const int col = (n0 - 2048) + wc * 32 + ni * 16 + lm;
        f16x4 o;
        o[0] = (f16)acc[mi][ni][0]; o[1] = (f16)acc[mi][ni][1];
        o[2] = (f16)acc[mi][ni][2]; o[3] = (f16)acc[mi][ni][3];
        *reinterpret_cast<f16x4*>(&vtb[(size_t)(b * 1024 + col) * SEQ + s]) = o;
      }
    }
  }
}

// ---------------- output GEMM: out = att @ Wo^T + bias + resid (f32) --------
// 128x64 tile + 2-phase dbuf (r16-proven). 1D grid 512; each XCD = exactly
// one 8x8 patch of the 16x32 grid (per-XCD working set 2 MB, L2-fit).
__global__ __launch_bounds__(256) void gemm_out(const f16* __restrict__ A,
                                                const f16* __restrict__ W,
                                                float* __restrict__ out,
                                                const float* __restrict__ bias,
                                                const float* __restrict__ resid) {
  __shared__ f16 sA[2][128][64];  // 32 KB
  __shared__ f16 sB[2][64][64];   // 16 KB
  const int t = threadIdx.x, l = t & 63, w = t >> 6;
  const int wr = w >> 1, wc = w & 1, lg = l >> 4, lm = l & 15;
  const int orig = blockIdx.x;
  const int c8 = orig & 7, j = orig >> 3;
  const int by = (c8 >> 1) * 8 + (j >> 3);
  const int bxn = (c8 & 1) * 8 + (j & 7);
  const int m0 = by * 128, n0 = bxn * 64;
  const int crow = l >> 3;
  const int scol = ((l & 7) ^ crow) << 3;
  const int rsw  = (lm & 7) << 3;

  f32x4 acc[4][2] = {};

  auto stage = [&](int buf, int k0) {
#pragma unroll
    for (int cc = 0; cc < 4; ++cc) {
      const int c = w + cc * 4;
      gload16(A + (size_t)(m0 + c * 8 + crow) * DM + k0 + scol, &sA[buf][c * 8][0]);
    }
#pragma unroll
    for (int cc = 0; cc < 2; ++cc) {
      const int c = w + cc * 4;
      gload16(W + (size_t)(n0 + c * 8 + crow) * DM + k0 + scol, &sB[buf][c * 8][0]);
    }
  };

  stage(0, 0);
  __syncthreads();
  int cur = 0;

  for (int it = 0; it < DM / 64; ++it) {
    if (it < DM / 64 - 1) stage(cur ^ 1, (it + 1) * 64);
#pragma unroll
    for (int kk = 0; kk < 2; ++kk) {
      f16x8 af[4], bf[2];
#pragma unroll
      for (int i = 0; i < 4; ++i)
        af[i] = *(const f16x8*)&sA[cur][wr * 64 + i * 16 + lm][(kk * 32 + lg * 8) ^ rsw];
#pragma unroll
      for (int i = 0; i < 2; ++i)
        bf[i] = *(const f16x8*)&sB[cur][wc * 32 + i * 16 + lm][(kk * 32 + lg * 8) ^ rsw];
      __builtin_amdgcn_s_setprio(1);
#pragma unroll
      for (int mi = 0; mi < 4; ++mi)
#pragma unroll
        for (int ni = 0; ni < 2; ++ni)
          acc[mi][ni] = mfma16(af[mi], bf[ni], acc[mi][ni]);
      __builtin_amdgcn_s_setprio(0);
    }
    __syncthreads();
    cur ^= 1;
  }

#pragma unroll
  for (int mi = 0; mi < 4; ++mi) {
    const int rowb = m0 + wr * 64 + mi * 16 + lg * 4;
#pragma unroll
    for (int ni = 0; ni < 2; ++ni) {
      const int col = n0 + wc * 32 + ni * 16 + lm;
#pragma unroll
      for (int r = 0; r < 4; ++r) {
        const size_t idx = (size_t)(rowb + r) * DM + col;
        out[idx] = resid[idx] + bias[col] + acc[mi][ni][r];
      }
    }
  }
}

// ---------------- attention: swapped-QK, KEY-SPLIT, SINGLE-buffered KV ------
// Block = 512 thr = 8 waves: wq=0..3 (q-sub, 32 rows), kg=0..1 (key group).
// Per kg: KVBLK=64, SINGLE buffer (sK+sV = 16 KB/kg, 32 KB data; 40 KB LDS
// incl. combine overlap) -> 4 blocks/CU = 32 waves/CU = 8 waves/SIMD.
// 2 barriers/tile; stalls covered by 8-deep wave TLP (launch_bounds(512,8)
// pins VGPR<=64). K staged ROW-PERMUTED (sigma) so swapped-QK output IS the
// PV A-fragment. No-max softmax -> key-split partials combine exactly.
__global__ __launch_bounds__(512, 8) void attn_kernel(const f16* __restrict__ Qb,
                                                      const f16* __restrict__ Kb,
                                                      const f16* __restrict__ Vt,
                                                      f16* __restrict__ Ob) {
  __shared__ __align__(16) char smem[40960];
  f16 (*sK)[64][64] = (f16(*)[64][64])smem;             // [kg][row][col] 16 KB
  f16 (*sV)[64][64] = (f16(*)[64][64])(smem + 16384);   // [kg][d][key]   16 KB
  float* cb = (float*)smem;  // combine buffer (40 KB), reused after last barrier

  // XCD-locality remap (512 blocks, 512%8==0 -> bijective)
  int bx = blockIdx.x;
  bx = (bx & 7) * 64 + (bx >> 3);
  const int qt = bx & 15, bh = bx >> 4;    // qt: 16 tiles of 128 q-rows
  const int h = bh & 15, b = bh >> 4;
  const int t = threadIdx.x, l = t & 63, w = t >> 6;
  const int kg = w >> 2, wq = w & 3;
  const int lg = l >> 4, lm = l & 15;
  const float K2 = 0.18033688f;  // (1/sqrt(64)) * log2(e)

  // Q frags (B operand) for 2 q-groups; rows = qt*128 + wq*32 + qg*16 + lm
  f16x8 qf[2][2];
#pragma unroll
  for (int qg = 0; qg < 2; ++qg) {
    const f16* qptr =
        Qb + (size_t)(b * SEQ + qt * 128 + wq * 32 + qg * 16 + lm) * DM + h * DKH;
    qf[qg][0] = *(const f16x8*)(qptr + lg * 8);
    qf[qg][1] = *(const f16x8*)(qptr + 32 + lg * 8);
#pragma unroll
    for (int j = 0; j < 8; ++j) {
      qf[qg][0][j] = (f16)((float)qf[qg][0][j] * K2);
      qf[qg][1][j] = (f16)((float)qf[qg][1][j] * K2);
    }
  }

  const f16x8 ones = {(f16)1, (f16)1, (f16)1, (f16)1,
                      (f16)1, (f16)1, (f16)1, (f16)1};

  f32x4 oacc[2][4] = {};
  f32x4 oden[2] = {};

  const int crow = l >> 3;                 // lane's row within 8-row chunk
  const int scol = ((l & 7) ^ crow) << 3;  // pre-swizzled source col (f16)
  const int rsw  = (lm & 7) << 3;          // read-side swizzle XOR (f16)

  // Hoisted staging pointers: 2 K-chunks + 2 V-chunks per wave per 64-key tile
  const f16* kptr[2];
  const f16* vptr[2];
#pragma unroll
  for (int cc = 0; cc < 2; ++cc) {
    const int c = wq + cc * 4;             // chunk 0..7 (8 rows each)
    const int krow = c * 8 + crow;         // 0..63
    // sigma(krow): (nf,lg,r) bits -> key = (nf>>1)*32 + lg*8 + (nf&1)*4 + r
    const int nfp = krow >> 4, lgp = (krow >> 2) & 3, rp = krow & 3;
    const int key = (nfp >> 1) * 32 + lgp * 8 + (nfp & 1) * 4 + rp;
    kptr[cc] = Kb + (size_t)(b * SEQ + kg * 1024 + key) * DM + h * DKH + scol;
    vptr[cc] = Vt + (size_t)(bh * DKH + c * 8 + crow) * SEQ + kg * 1024 + scol;
  }

  auto stage = [&]() {
#pragma unroll
    for (int cc = 0; cc < 2; ++cc) {
      const int c = wq + cc * 4;
      gload16(kptr[cc], &sK[kg][c * 8][0]);
      gload16(vptr[cc], &sV[kg][c * 8][0]);
      kptr[cc] += 64 * DM;
      vptr[cc] += 64;
    }
  };

  union PU { f16x8 v; f16x2 hh[4]; };

  for (int kt = 0; kt < 16; ++kt) {        // 16 x 64-key tiles per key-group
    stage();
    __syncthreads();

    // swapped QK^T: D[key][q]; kf shared across both q-groups
    f32x4 sc[2][4] = {};
    __builtin_amdgcn_s_setprio(1);
#pragma unroll
    for (int kk = 0; kk < 2; ++kk)
#pragma unroll
      for (int nf = 0; nf < 4; ++nf) {
        f16x8 kf = *(const f16x8*)
            &sK[kg][nf * 16 + lm][(kk * 32 + lg * 8) ^ rsw];
        sc[0][nf] = mfma16(kf, qf[0][kk], sc[0][nf]);
        sc[1][nf] = mfma16(kf, qf[1][kk], sc[1][nf]);
      }
    __builtin_amdgcn_s_setprio(0);

    // P = exp2(s), packed pairwise straight into PV A-fragments
    PU pu[2][2];
#pragma unroll
    for (int qg = 0; qg < 2; ++qg)
#pragma unroll
      for (int nf = 0; nf < 4; ++nf) {
        float e0 = __builtin_amdgcn_exp2f(sc[qg][nf][0]);
        float e1 = __builtin_amdgcn_exp2f(sc[qg][nf][1]);
        float e2 = __builtin_amdgcn_exp2f(sc[qg][nf][2]);
        float e3 = __builtin_amdgcn_exp2f(sc[qg][nf][3]);
        pu[qg][nf >> 1].hh[(nf & 1) * 2 + 0] = cvt_pk(e0, e1);
        pu[qg][nf >> 1].hh[(nf & 1) * 2 + 1] = cvt_pk(e2, e3);
      }

    // PV (+den)
    __builtin_amdgcn_s_setprio(1);
#pragma unroll
    for (int ks = 0; ks < 2; ++ks) {
#pragma unroll
      for (int ni = 0; ni < 4; ++ni) {
        f16x8 vf = *(const f16x8*)
            &sV[kg][ni * 16 + lm][(ks * 32 + lg * 8) ^ rsw];
        oacc[0][ni] = mfma16(pu[0][ks].v, vf, oacc[0][ni]);
        oacc[1][ni] = mfma16(pu[1][ks].v, vf, oacc[1][ni]);
      }
      oden[0] = mfma16(pu[0][ks].v, ones, oden[0]);
      oden[1] = mfma16(pu[1][ks].v, ones, oden[1]);
    }
    __builtin_amdgcn_s_setprio(0);

    __syncthreads();   // readers done before next stage overwrites
  }

  // ---- key-group combine: kg=1 dumps partials, kg=0 adds + writes ----------
  float* myp = cb + (size_t)(wq * 64 + l) * 40;
  if (kg == 1) {
#pragma unroll
    for (int qg = 0; qg < 2; ++qg)
#pragma unroll
      for (int ni = 0; ni < 4; ++ni)
#pragma unroll
        for (int r = 0; r < 4; ++r) myp[qg * 16 + ni * 4 + r] = oacc[qg][ni][r];
#pragma unroll
    for (int qg = 0; qg < 2; ++qg)
#pragma unroll
      for (int r = 0; r < 4; ++r) myp[32 + qg * 4 + r] = oden[qg][r];
  }
  __syncthreads();
  if (kg == 0) {
#pragma unroll
    for (int qg = 0; qg < 2; ++qg) {
#pragma unroll
      for (int ni = 0; ni < 4; ++ni)
#pragma unroll
        for (int r = 0; r < 4; ++r) oacc[qg][ni][r] += myp[qg * 16 + ni * 4 + r];
      float rd[4];
#pragma unroll
      for (int r = 0; r < 4; ++r)
        rd[r] = 1.f / (oden[qg][r] + myp[32 + qg * 4 + r]);
#pragma unroll
      for (int ni = 0; ni < 4; ++ni)
#pragma unroll
        for (int r = 0; r < 4; ++r) {
          const int q = qt * 128 + wq * 32 + qg * 16 + lg * 4 + r;
          const int d = ni * 16 + lm;
          Ob[(size_t)(b * SEQ + q) * DM + h * DKH + d] =
              (f16)(oacc[qg][ni][r] * rd[r]);
        }
    }
  }
}

// ---------------- launch ----------------
extern "C" void kernel_launch(void* const* d_in, const int* in_sizes, int n_in,
                              void* d_out, int out_size, void* d_ws, size_t ws_size,
                              hipStream_t stream) {
  const float* x   = (const float*)d_in[0];
  const float* w_q = (const float*)d_in[1];
  const float* w_k = (const float*)d_in[2];
  const float* w_v = (const float*)d_in[3];
  const float* w_o = (const float*)d_in[4];
  const float* b_o = (const float*)d_in[5];
  const float* lng = (const float*)d_in[6];
  const float* lnb = (const float*)d_in[7];
  float* out = (float*)d_out;

  char* ws = (char*)d_ws;
  const size_t MB = 1ull << 20;
  f16* xn   = (f16*)(ws + 0 * MB);   // 8 MB
  f16* wqkv = (f16*)(ws + 8 * MB);   // 6 MB [3072][1024] (+2 MB wo, contiguous)
  f16* woh  = (f16*)(ws + 14 * MB);  // 2 MB
  f16* qb   = (f16*)(ws + 16 * MB);  // 8 MB
  f16* kb   = (f16*)(ws + 24 * MB);  // 8 MB
  f16* vtb  = (f16*)(ws + 32 * MB);  // 8 MB
  f16* att  = (f16*)(ws + 40 * MB);  // 8 MB

  prep_kernel<<<8192, 256, 0, stream>>>(x, w_q, w_k, w_v, w_o, lng, lnb, wqkv, xn);
  gemm_qkv<<<1536, 256, 0, stream>>>(xn, wqkv, qb, kb, vtb);
  attn_kernel<<<512, 512, 0, stream>>>(qb, kb, vtb, att);
  gemm_out<<<512, 256, 0, stream>>>(att, woh, out, b_o, x);
}

// Round 21
// 104.547 us; speedup vs baseline: 2.8297x; 2.8297x over previous
//
#include <hip/hip_runtime.h>

typedef _Float16 f16;
typedef _Float16 f16x8 __attribute__((ext_vector_type(8)));
typedef _Float16 f16x4 __attribute__((ext_vector_type(4)));
typedef _Float16 f16x2 __attribute__((ext_vector_type(2)));
typedef __fp16 fp16x2 __attribute__((ext_vector_type(2)));
typedef float f32x4 __attribute__((ext_vector_type(4)));

#define SEQ   2048
#define DM    1024
#define DKH   64
#define MTOT  4096  // B*S

__device__ __forceinline__ f32x4 mfma16(f16x8 a, f16x8 b, f32x4 c) {
  return __builtin_amdgcn_mfma_f32_16x16x32_f16(a, b, c, 0, 0, 0);
}

__device__ __forceinline__ f16x2 cvt_pk(float a, float b) {
  fp16x2 r = __builtin_amdgcn_cvt_pkrtz(a, b);
  return __builtin_bit_cast(f16x2, r);
}

// async global->LDS, 16B per lane; LDS dest = uniform base + lane*16 (HW rule)
__device__ __forceinline__ void gload16(const f16* g, f16* l) {
  __builtin_amdgcn_global_load_lds(
      (const __attribute__((address_space(1))) void*)g,
      (__attribute__((address_space(3))) void*)l, 16, 0, 0);
}

// ------- merged prep: blocks 0..4095 cast weights, 4096..8191 LayerNorm -----
__global__ __launch_bounds__(256) void prep_kernel(const float* __restrict__ x,
                                                   const float* __restrict__ w_q,
                                                   const float* __restrict__ w_k,
                                                   const float* __restrict__ w_v,
                                                   const float* __restrict__ w_o,
                                                   const float* __restrict__ gamma,
                                                   const float* __restrict__ beta,
                                                   f16* __restrict__ wout,
                                                   f16* __restrict__ xn) {
  const int t = threadIdx.x;
  if (blockIdx.x < 4096) {
    const int sel = blockIdx.x >> 10;
    const float* src = sel == 0 ? w_q : sel == 1 ? w_k : sel == 2 ? w_v : w_o;
    const int i = ((blockIdx.x & 1023) * 256 + t) * 4;
    float4 v = *reinterpret_cast<const float4*>(src + i);
    f16x4 o;
    o[0] = (f16)v.x; o[1] = (f16)v.y; o[2] = (f16)v.z; o[3] = (f16)v.w;
    *reinterpret_cast<f16x4*>(wout + (size_t)sel * 1048576 + i) = o;
    return;
  }
  const int row = blockIdx.x - 4096;
  const float* xr = x + (size_t)row * DM;
  float v[4], s = 0.f, s2 = 0.f;
#pragma unroll
  for (int i = 0; i < 4; ++i) {
    v[i] = xr[t + i * 256];
    s += v[i];
    s2 += v[i] * v[i];
  }
#pragma unroll
  for (int o = 32; o > 0; o >>= 1) {
    s  += __shfl_down(s, o);
    s2 += __shfl_down(s2, o);
  }
  __shared__ float ps[4], ps2[4], mu_s, rs_s;
  if ((t & 63) == 0) { ps[t >> 6] = s; ps2[t >> 6] = s2; }
  __syncthreads();
  if (t == 0) {
    float a = ps[0] + ps[1] + ps[2] + ps[3];
    float b = ps2[0] + ps2[1] + ps2[2] + ps2[3];
    float mu = a * (1.f / DM);
    float var = b * (1.f / DM) - mu * mu;
    mu_s = mu;
    rs_s = rsqrtf(var + 1e-5f);
  }
  __syncthreads();
  const float mu = mu_s, rs = rs_s;
#pragma unroll
  for (int i = 0; i < 4; ++i) {
    int d = t + i * 256;
    xn[(size_t)row * DM + d] = (f16)(((v[i] - mu) * rs) * gamma[d] + beta[d]);
  }
}

// ---------------- fused QKV GEMM: C[M,3072] = xn @ Wqkv^T --------------------
// 128x64 tile + 2-phase dbuf (r16-proven schedule). 1D grid 1536 with
// 8x8 PATCH-MAJOR XCD decomposition (r19-proven): per-XCD working set ~3 MB
// (L2-fit) -> staging loads are L2 hits.
__global__ __launch_bounds__(256) void gemm_qkv(const f16* __restrict__ A,
                                                const f16* __restrict__ Wqkv,
                                                f16* __restrict__ qb,
                                                f16* __restrict__ kb,
                                                f16* __restrict__ vtb) {
  __shared__ f16 sA[2][128][64];  // 32 KB
  __shared__ f16 sB[2][64][64];   // 16 KB
  const int t = threadIdx.x, l = t & 63, w = t >> 6;
  const int wr = w >> 1, wc = w & 1, lg = l >> 4, lm = l & 15;
  // patch-major remap: XCD c = orig%8 gets u = c*192 + orig/8; 8x8 patches
  const int orig = blockIdx.x;
  const int u = (orig & 7) * 192 + (orig >> 3);
  const int g = u >> 6, wj = u & 63;
  const int by = (g / 6) * 8 + (wj >> 3);
  const int bxn = (g % 6) * 8 + (wj & 7);
  const int m0 = by * 128, n0 = bxn * 64;
  const int crow = l >> 3;                 // lane's row within 8-row chunk
  const int scol = ((l & 7) ^ crow) << 3;  // pre-swizzled source col (f16)
  const int rsw  = (lm & 7) << 3;          // read-side swizzle XOR (f16)

  f32x4 acc[4][2] = {};

  auto stage = [&](int buf, int k0) {
#pragma unroll
    for (int cc = 0; cc < 4; ++cc) {
      const int c = w + cc * 4;            // chunk 0..15 (8 rows each)
      gload16(A + (size_t)(m0 + c * 8 + crow) * DM + k0 + scol, &sA[buf][c * 8][0]);
    }
#pragma unroll
    for (int cc = 0; cc < 2; ++cc) {
      const int c = w + cc * 4;            // chunk 0..7
      gload16(Wqkv + (size_t)(n0 + c * 8 + crow) * DM + k0 + scol, &sB[buf][c * 8][0]);
    }
  };

  stage(0, 0);
  __syncthreads();
  int cur = 0;

  for (int it = 0; it < DM / 64; ++it) {
    if (it < DM / 64 - 1) stage(cur ^ 1, (it + 1) * 64);
#pragma unroll
    for (int kk = 0; kk < 2; ++kk) {
      f16x8 af[4], bf[2];
#pragma unroll
      for (int i = 0; i < 4; ++i)
        af[i] = *(const f16x8*)&sA[cur][wr * 64 + i * 16 + lm][(kk * 32 + lg * 8) ^ rsw];
#pragma unroll
      for (int i = 0; i < 2; ++i)
        bf[i] = *(const f16x8*)&sB[cur][wc * 32 + i * 16 + lm][(kk * 32 + lg * 8) ^ rsw];
      __builtin_amdgcn_s_setprio(1);
#pragma unroll
      for (int mi = 0; mi < 4; ++mi)
#pragma unroll
        for (int ni = 0; ni < 2; ++ni)
          acc[mi][ni] = mfma16(af[mi], bf[ni], acc[mi][ni]);
      __builtin_amdgcn_s_setprio(0);
    }
    __syncthreads();
    cur ^= 1;
  }

  const int sel = bxn >> 4;  // 0:Q 1:K 2:V  (16 n-blocks per matrix)
  if (sel < 2) {
    f16* outp = sel == 0 ? qb : kb;
    const int nloc = n0 - sel * 1024;
#pragma unroll
    for (int mi = 0; mi < 4; ++mi) {
      const int rowb = m0 + wr * 64 + mi * 16 + lg * 4;
#pragma unroll
      for (int ni = 0; ni < 2; ++ni) {
        const int col = nloc + wc * 32 + ni * 16 + lm;
#pragma unroll
        for (int r = 0; r < 4; ++r)
          outp[(size_t)(rowb + r) * DM + col] = (f16)acc[mi][ni][r];
      }
    }
  } else {
    // V: write transposed. global row m = b*2048+s ; col = h*64+d
    // Vt idx = (b*1024 + col)*SEQ + s ; r (=s) contiguous -> packed 8B store
#pragma unroll
    for (int mi = 0; mi < 4; ++mi) {
      const int rowb = m0 + wr * 64 + mi * 16 + lg * 4;
      const int b = rowb >> 11, s = rowb & 2047;
#pragma unroll
      for (int ni = 0; ni < 2; ++ni) {
        const int col = (n0 - 2048) + wc * 32 + ni * 16 + lm;
        f16x4 o;
        o[0] = (f16)acc[mi][ni][0]; o[1] = (f16)acc[mi][ni][1];
        o[2] = (f16)acc[mi][ni][2]; o[3] = (f16)acc[mi][ni][3];
        *reinterpret_cast<f16x4*>(&vtb[(size_t)(b * 1024 + col) * SEQ + s]) = o;
      }
    }
  }
}

// ---------------- output GEMM: out = att @ Wo^T + bias + resid (f32) --------
// 128x64 tile + 2-phase dbuf (r16-proven). 1D grid 512; each XCD = exactly
// one 8x8 patch of the 16x32 grid (per-XCD working set 2 MB, L2-fit).
__global__ __launch_bounds__(256) void gemm_out(const f16* __restrict__ A,
                                                const f16* __restrict__ W,
                                                float* __restrict__ out,
                                                const float* __restrict__ bias,
                                                const float* __restrict__ resid) {
  __shared__ f16 sA[2][128][64];  // 32 KB
  __shared__ f16 sB[2][64][64];   // 16 KB
  const int t = threadIdx.x, l = t & 63, w = t >> 6;
  const int wr = w >> 1, wc = w & 1, lg = l >> 4, lm = l & 15;
  const int orig = blockIdx.x;
  const int c8 = orig & 7, j = orig >> 3;
  const int by = (c8 >> 1) * 8 + (j >> 3);
  const int bxn = (c8 & 1) * 8 + (j & 7);
  const int m0 = by * 128, n0 = bxn * 64;
  const int crow = l >> 3;
  const int scol = ((l & 7) ^ crow) << 3;
  const int rsw  = (lm & 7) << 3;

  f32x4 acc[4][2] = {};

  auto stage = [&](int buf, int k0) {
#pragma unroll
    for (int cc = 0; cc < 4; ++cc) {
      const int c = w + cc * 4;
      gload16(A + (size_t)(m0 + c * 8 + crow) * DM + k0 + scol, &sA[buf][c * 8][0]);
    }
#pragma unroll
    for (int cc = 0; cc < 2; ++cc) {
      const int c = w + cc * 4;
      gload16(W + (size_t)(n0 + c * 8 + crow) * DM + k0 + scol, &sB[buf][c * 8][0]);
    }
  };

  stage(0, 0);
  __syncthreads();
  int cur = 0;

  for (int it = 0; it < DM / 64; ++it) {
    if (it < DM / 64 - 1) stage(cur ^ 1, (it + 1) * 64);
#pragma unroll
    for (int kk = 0; kk < 2; ++kk) {
      f16x8 af[4], bf[2];
#pragma unroll
      for (int i = 0; i < 4; ++i)
        af[i] = *(const f16x8*)&sA[cur][wr * 64 + i * 16 + lm][(kk * 32 + lg * 8) ^ rsw];
#pragma unroll
      for (int i = 0; i < 2; ++i)
        bf[i] = *(const f16x8*)&sB[cur][wc * 32 + i * 16 + lm][(kk * 32 + lg * 8) ^ rsw];
      __builtin_amdgcn_s_setprio(1);
#pragma unroll
      for (int mi = 0; mi < 4; ++mi)
#pragma unroll
        for (int ni = 0; ni < 2; ++ni)
          acc[mi][ni] = mfma16(af[mi], bf[ni], acc[mi][ni]);
      __builtin_amdgcn_s_setprio(0);
    }
    __syncthreads();
    cur ^= 1;
  }

#pragma unroll
  for (int mi = 0; mi < 4; ++mi) {
    const int rowb = m0 + wr * 64 + mi * 16 + lg * 4;
#pragma unroll
    for (int ni = 0; ni < 2; ++ni) {
      const int col = n0 + wc * 32 + ni * 16 + lm;
#pragma unroll
      for (int r = 0; r < 4; ++r) {
        const size_t idx = (size_t)(rowb + r) * DM + col;
        out[idx] = resid[idx] + bias[col] + acc[mi][ni][r];
      }
    }
  }
}

// ---------------- attention: swapped-QK, KEY-SPLIT, SINGLE-buffered KV ------
// Block = 512 thr = 8 waves: wq=0..3 (q-sub, 32 rows), kg=0..1 (key group).
// Per kg: KVBLK=64, SINGLE buffer (32 KB data; 40 KB LDS incl. combine
// overlap) -> LDS allows 4 blocks/CU = 32 waves/CU. launch_bounds(512,4)
// (NOT 8 — r20's (512,8) clamped VGPR to 32 and spilled catastrophically);
// compiler's natural ~64 VGPR still permits 8 waves/SIMD.
// K staged ROW-PERMUTED (sigma) so swapped-QK output IS the PV A-fragment.
// No-max softmax -> key-split partials combine exactly via LDS at the end.
__global__ __launch_bounds__(512, 4) void attn_kernel(const f16* __restrict__ Qb,
                                                      const f16* __restrict__ Kb,
                                                      const f16* __restrict__ Vt,
                                                      f16* __restrict__ Ob) {
  __shared__ __align__(16) char smem[40960];
  f16 (*sK)[64][64] = (f16(*)[64][64])smem;             // [kg][row][col] 16 KB
  f16 (*sV)[64][64] = (f16(*)[64][64])(smem + 16384);   // [kg][d][key]   16 KB
  float* cb = (float*)smem;  // combine buffer (40 KB), reused after last barrier

  // XCD-locality remap (512 blocks, 512%8==0 -> bijective)
  int bx = blockIdx.x;
  bx = (bx & 7) * 64 + (bx >> 3);
  const int qt = bx & 15, bh = bx >> 4;    // qt: 16 tiles of 128 q-rows
  const int h = bh & 15, b = bh >> 4;
  const int t = threadIdx.x, l = t & 63, w = t >> 6;
  const int kg = w >> 2, wq = w & 3;
  const int lg = l >> 4, lm = l & 15;
  const float K2 = 0.18033688f;  // (1/sqrt(64)) * log2(e)

  // Q frags (B operand) for 2 q-groups; rows = qt*128 + wq*32 + qg*16 + lm
  f16x8 qf[2][2];
#pragma unroll
  for (int qg = 0; qg < 2; ++qg) {
    const f16* qptr =
        Qb + (size_t)(b * SEQ + qt * 128 + wq * 32 + qg * 16 + lm) * DM + h * DKH;
    qf[qg][0] = *(const f16x8*)(qptr + lg * 8);
    qf[qg][1] = *(const f16x8*)(qptr + 32 + lg * 8);
#pragma unroll
    for (int j = 0; j < 8; ++j) {
      qf[qg][0][j] = (f16)((float)qf[qg][0][j] * K2);
      qf[qg][1][j] = (f16)((float)qf[qg][1][j] * K2);
    }
  }

  const f16x8 ones = {(f16)1, (f16)1, (f16)1, (f16)1,
                      (f16)1, (f16)1, (f16)1, (f16)1};

  f32x4 oacc[2][4] = {};
  f32x4 oden[2] = {};

  const int crow = l >> 3;                 // lane's row within 8-row chunk
  const int scol = ((l & 7) ^ crow) << 3;  // pre-swizzled source col (f16)
  const int rsw  = (lm & 7) << 3;          // read-side swizzle XOR (f16)

  // Hoisted staging pointers: 2 K-chunks + 2 V-chunks per wave per 64-key tile
  const f16* kptr[2];
  const f16* vptr[2];
#pragma unroll
  for (int cc = 0; cc < 2; ++cc) {
    const int c = wq + cc * 4;             // chunk 0..7 (8 rows each)
    const int krow = c * 8 + crow;         // 0..63
    // sigma(krow): (nf,lg,r) bits -> key = (nf>>1)*32 + lg*8 + (nf&1)*4 + r
    const int nfp = krow >> 4, lgp = (krow >> 2) & 3, rp = krow & 3;
    const int key = (nfp >> 1) * 32 + lgp * 8 + (nfp & 1) * 4 + rp;
    kptr[cc] = Kb + (size_t)(b * SEQ + kg * 1024 + key) * DM + h * DKH + scol;
    vptr[cc] = Vt + (size_t)(bh * DKH + c * 8 + crow) * SEQ + kg * 1024 + scol;
  }

  auto stage = [&]() {
#pragma unroll
    for (int cc = 0; cc < 2; ++cc) {
      const int c = wq + cc * 4;
      gload16(kptr[cc], &sK[kg][c * 8][0]);
      gload16(vptr[cc], &sV[kg][c * 8][0]);
      kptr[cc] += 64 * DM;
      vptr[cc] += 64;
    }
  };

  union PU { f16x8 v; f16x2 hh[4]; };

  for (int kt = 0; kt < 16; ++kt) {        // 16 x 64-key tiles per key-group
    stage();
    __syncthreads();

    // swapped QK^T: D[key][q]; kf shared across both q-groups
    f32x4 sc[2][4] = {};
    __builtin_amdgcn_s_setprio(1);
#pragma unroll
    for (int kk = 0; kk < 2; ++kk)
#pragma unroll
      for (int nf = 0; nf < 4; ++nf) {
        f16x8 kf = *(const f16x8*)
            &sK[kg][nf * 16 + lm][(kk * 32 + lg * 8) ^ rsw];
        sc[0][nf] = mfma16(kf, qf[0][kk], sc[0][nf]);
        sc[1][nf] = mfma16(kf, qf[1][kk], sc[1][nf]);
      }
    __builtin_amdgcn_s_setprio(0);

    // P = exp2(s), packed pairwise straight into PV A-fragments
    PU pu[2][2];
#pragma unroll
    for (int qg = 0; qg < 2; ++qg)
#pragma unroll
      for (int nf = 0; nf < 4; ++nf) {
        float e0 = __builtin_amdgcn_exp2f(sc[qg][nf][0]);
        float e1 = __builtin_amdgcn_exp2f(sc[qg][nf][1]);
        float e2 = __builtin_amdgcn_exp2f(sc[qg][nf][2]);
        float e3 = __builtin_amdgcn_exp2f(sc[qg][nf][3]);
        pu[qg][nf >> 1].hh[(nf & 1) * 2 + 0] = cvt_pk(e0, e1);
        pu[qg][nf >> 1].hh[(nf & 1) * 2 + 1] = cvt_pk(e2, e3);
      }

    // PV (+den)
    __builtin_amdgcn_s_setprio(1);
#pragma unroll
    for (int ks = 0; ks < 2; ++ks) {
#pragma unroll
      for (int ni = 0; ni < 4; ++ni) {
        f16x8 vf = *(const f16x8*)
            &sV[kg][ni * 16 + lm][(ks * 32 + lg * 8) ^ rsw];
        oacc[0][ni] = mfma16(pu[0][ks].v, vf, oacc[0][ni]);
        oacc[1][ni] = mfma16(pu[1][ks].v, vf, oacc[1][ni]);
      }
      oden[0] = mfma16(pu[0][ks].v, ones, oden[0]);
      oden[1] = mfma16(pu[1][ks].v, ones, oden[1]);
    }
    __builtin_amdgcn_s_setprio(0);

    __syncthreads();   // readers done before next stage overwrites
  }

  // ---- key-group combine: kg=1 dumps partials, kg=0 adds + writes ----------
  float* myp = cb + (size_t)(wq * 64 + l) * 40;
  if (kg == 1) {
#pragma unroll
    for (int qg = 0; qg < 2; ++qg)
#pragma unroll
      for (int ni = 0; ni < 4; ++ni)
#pragma unroll
        for (int r = 0; r < 4; ++r) myp[qg * 16 + ni * 4 + r] = oacc[qg][ni][r];
#pragma unroll
    for (int qg = 0; qg < 2; ++qg)
#pragma unroll
      for (int r = 0; r < 4; ++r) myp[32 + qg * 4 + r] = oden[qg][r];
  }
  __syncthreads();
  if (kg == 0) {
#pragma unroll
    for (int qg = 0; qg < 2; ++qg) {
#pragma unroll
      for (int ni = 0; ni < 4; ++ni)
#pragma unroll
        for (int r = 0; r < 4; ++r) oacc[qg][ni][r] += myp[qg * 16 + ni * 4 + r];
      float rd[4];
#pragma unroll
      for (int r = 0; r < 4; ++r)
        rd[r] = 1.f / (oden[qg][r] + myp[32 + qg * 4 + r]);
#pragma unroll
      for (int ni = 0; ni < 4; ++ni)
#pragma unroll
        for (int r = 0; r < 4; ++r) {
          const int q = qt * 128 + wq * 32 + qg * 16 + lg * 4 + r;
          const int d = ni * 16 + lm;
          Ob[(size_t)(b * SEQ + q) * DM + h * DKH + d] =
              (f16)(oacc[qg][ni][r] * rd[r]);
        }
    }
  }
}

// ---------------- launch ----------------
extern "C" void kernel_launch(void* const* d_in, const int* in_sizes, int n_in,
                              void* d_out, int out_size, void* d_ws, size_t ws_size,
                              hipStream_t stream) {
  const float* x   = (const float*)d_in[0];
  const float* w_q = (const float*)d_in[1];
  const float* w_k = (const float*)d_in[2];
  const float* w_v = (const float*)d_in[3];
  const float* w_o = (const float*)d_in[4];
  const float* b_o = (const float*)d_in[5];
  const float* lng = (const float*)d_in[6];
  const float* lnb = (const float*)d_in[7];
  float* out = (float*)d_out;

  char* ws = (char*)d_ws;
  const size_t MB = 1ull << 20;
  f16* xn   = (f16*)(ws + 0 * MB);   // 8 MB
  f16* wqkv = (f16*)(ws + 8 * MB);   // 6 MB [3072][1024] (+2 MB wo, contiguous)
  f16* woh  = (f16*)(ws + 14 * MB);  // 2 MB
  f16* qb   = (f16*)(ws + 16 * MB);  // 8 MB
  f16* kb   = (f16*)(ws + 24 * MB);  // 8 MB
  f16* vtb  = (f16*)(ws + 32 * MB);  // 8 MB
  f16* att  = (f16*)(ws + 40 * MB);  // 8 MB

  prep_kernel<<<8192, 256, 0, stream>>>(x, w_q, w_k, w_v, w_o, lng, lnb, wqkv, xn);
  gemm_qkv<<<1536, 256, 0, stream>>>(xn, wqkv, qb, kb, vtb);
  attn_kernel<<<512, 512, 0, stream>>>(qb, kb, vtb, att);
  gemm_out<<<512, 256, 0, stream>>>(att, woh, out, b_o, x);
}

// Round 22
// 103.517 us; speedup vs baseline: 2.8579x; 1.0099x over previous
//
#include <hip/hip_runtime.h>

typedef _Float16 f16;
typedef _Float16 f16x8 __attribute__((ext_vector_type(8)));
typedef _Float16 f16x4 __attribute__((ext_vector_type(4)));
typedef _Float16 f16x2 __attribute__((ext_vector_type(2)));
typedef __fp16 fp16x2 __attribute__((ext_vector_type(2)));
typedef float f32x4 __attribute__((ext_vector_type(4)));

#define SEQ   2048
#define DM    1024
#define DKH   64
#define MTOT  4096  // B*S

__device__ __forceinline__ f32x4 mfma16(f16x8 a, f16x8 b, f32x4 c) {
  return __builtin_amdgcn_mfma_f32_16x16x32_f16(a, b, c, 0, 0, 0);
}

__device__ __forceinline__ f16x2 cvt_pk(float a, float b) {
  fp16x2 r = __builtin_amdgcn_cvt_pkrtz(a, b);
  return __builtin_bit_cast(f16x2, r);
}

// async global->LDS, 16B per lane; LDS dest = uniform base + lane*16 (HW rule)
__device__ __forceinline__ void gload16(const f16* g, f16* l) {
  __builtin_amdgcn_global_load_lds(
      (const __attribute__((address_space(1))) void*)g,
      (__attribute__((address_space(3))) void*)l, 16, 0, 0);
}

// ------- merged prep: blocks 0..4095 cast weights, 4096..8191 LayerNorm -----
__global__ __launch_bounds__(256) void prep_kernel(const float* __restrict__ x,
                                                   const float* __restrict__ w_q,
                                                   const float* __restrict__ w_k,
                                                   const float* __restrict__ w_v,
                                                   const float* __restrict__ w_o,
                                                   const float* __restrict__ gamma,
                                                   const float* __restrict__ beta,
                                                   f16* __restrict__ wout,
                                                   f16* __restrict__ xn) {
  const int t = threadIdx.x;
  if (blockIdx.x < 4096) {
    const int sel = blockIdx.x >> 10;
    const float* src = sel == 0 ? w_q : sel == 1 ? w_k : sel == 2 ? w_v : w_o;
    const int i = ((blockIdx.x & 1023) * 256 + t) * 4;
    float4 v = *reinterpret_cast<const float4*>(src + i);
    f16x4 o;
    o[0] = (f16)v.x; o[1] = (f16)v.y; o[2] = (f16)v.z; o[3] = (f16)v.w;
    *reinterpret_cast<f16x4*>(wout + (size_t)sel * 1048576 + i) = o;
    return;
  }
  const int row = blockIdx.x - 4096;
  const float* xr = x + (size_t)row * DM;
  float4 v = *reinterpret_cast<const float4*>(xr + t * 4);
  float s = v.x + v.y + v.z + v.w;
  float s2 = v.x * v.x + v.y * v.y + v.z * v.z + v.w * v.w;
#pragma unroll
  for (int o = 32; o > 0; o >>= 1) {
    s  += __shfl_down(s, o);
    s2 += __shfl_down(s2, o);
  }
  __shared__ float ps[4], ps2[4], mu_s, rs_s;
  if ((t & 63) == 0) { ps[t >> 6] = s; ps2[t >> 6] = s2; }
  __syncthreads();
  if (t == 0) {
    float a = ps[0] + ps[1] + ps[2] + ps[3];
    float b = ps2[0] + ps2[1] + ps2[2] + ps2[3];
    float mu = a * (1.f / DM);
    float var = b * (1.f / DM) - mu * mu;
    mu_s = mu;
    rs_s = rsqrtf(var + 1e-5f);
  }
  __syncthreads();
  const float mu = mu_s, rs = rs_s;
  float4 g4 = *reinterpret_cast<const float4*>(gamma + t * 4);
  float4 b4 = *reinterpret_cast<const float4*>(beta + t * 4);
  f16x4 o;
  o[0] = (f16)(((v.x - mu) * rs) * g4.x + b4.x);
  o[1] = (f16)(((v.y - mu) * rs) * g4.y + b4.y);
  o[2] = (f16)(((v.z - mu) * rs) * g4.z + b4.z);
  o[3] = (f16)(((v.w - mu) * rs) * g4.w + b4.w);
  *reinterpret_cast<f16x4*>(xn + (size_t)row * DM + t * 4) = o;
}

// ---------------- fused QKV GEMM: C[M,3072] = xn @ Wqkv^T --------------------
// 128x64 tile + 2-phase dbuf (r16-proven schedule). 1D grid 1536 with
// 8x8 PATCH-MAJOR XCD decomposition (r19-proven): per-XCD working set ~3 MB
// (L2-fit) -> staging loads are L2 hits.
__global__ __launch_bounds__(256) void gemm_qkv(const f16* __restrict__ A,
                                                const f16* __restrict__ Wqkv,
                                                f16* __restrict__ qb,
                                                f16* __restrict__ kb,
                                                f16* __restrict__ vtb) {
  __shared__ f16 sA[2][128][64];  // 32 KB
  __shared__ f16 sB[2][64][64];   // 16 KB
  const int t = threadIdx.x, l = t & 63, w = t >> 6;
  const int wr = w >> 1, wc = w & 1, lg = l >> 4, lm = l & 15;
  // patch-major remap: XCD c = orig%8 gets u = c*192 + orig/8; 8x8 patches
  const int orig = blockIdx.x;
  const int u = (orig & 7) * 192 + (orig >> 3);
  const int g = u >> 6, wj = u & 63;
  const int by = (g / 6) * 8 + (wj >> 3);
  const int bxn = (g % 6) * 8 + (wj & 7);
  const int m0 = by * 128, n0 = bxn * 64;
  const int crow = l >> 3;                 // lane's row within 8-row chunk
  const int scol = ((l & 7) ^ crow) << 3;  // pre-swizzled source col (f16)
  const int rsw  = (lm & 7) << 3;          // read-side swizzle XOR (f16)

  f32x4 acc[4][2] = {};

  auto stage = [&](int buf, int k0) {
#pragma unroll
    for (int cc = 0; cc < 4; ++cc) {
      const int c = w + cc * 4;            // chunk 0..15 (8 rows each)
      gload16(A + (size_t)(m0 + c * 8 + crow) * DM + k0 + scol, &sA[buf][c * 8][0]);
    }
#pragma unroll
    for (int cc = 0; cc < 2; ++cc) {
      const int c = w + cc * 4;            // chunk 0..7
      gload16(Wqkv + (size_t)(n0 + c * 8 + crow) * DM + k0 + scol, &sB[buf][c * 8][0]);
    }
  };

  stage(0, 0);
  __syncthreads();
  int cur = 0;

  for (int it = 0; it < DM / 64; ++it) {
    if (it < DM / 64 - 1) stage(cur ^ 1, (it + 1) * 64);
#pragma unroll
    for (int kk = 0; kk < 2; ++kk) {
      f16x8 af[4], bf[2];
#pragma unroll
      for (int i = 0; i < 4; ++i)
        af[i] = *(const f16x8*)&sA[cur][wr * 64 + i * 16 + lm][(kk * 32 + lg * 8) ^ rsw];
#pragma unroll
      for (int i = 0; i < 2; ++i)
        bf[i] = *(const f16x8*)&sB[cur][wc * 32 + i * 16 + lm][(kk * 32 + lg * 8) ^ rsw];
      __builtin_amdgcn_s_setprio(1);
#pragma unroll
      for (int mi = 0; mi < 4; ++mi)
#pragma unroll
        for (int ni = 0; ni < 2; ++ni)
          acc[mi][ni] = mfma16(af[mi], bf[ni], acc[mi][ni]);
      __builtin_amdgcn_s_setprio(0);
    }
    __syncthreads();
    cur ^= 1;
  }

  const int sel = bxn >> 4;  // 0:Q 1:K 2:V  (16 n-blocks per matrix)
  if (sel < 2) {
    f16* outp = sel == 0 ? qb : kb;
    const int nloc = n0 - sel * 1024;
#pragma unroll
    for (int mi = 0; mi < 4; ++mi) {
      const int rowb = m0 + wr * 64 + mi * 16 + lg * 4;
#pragma unroll
      for (int ni = 0; ni < 2; ++ni) {
        const int col = nloc + wc * 32 + ni * 16 + lm;
#pragma unroll
        for (int r = 0; r < 4; ++r)
          outp[(size_t)(rowb + r) * DM + col] = (f16)acc[mi][ni][r];
      }
    }
  } else {
    // V: write transposed. global row m = b*2048+s ; col = h*64+d
    // Vt idx = (b*1024 + col)*SEQ + s ; r (=s) contiguous -> packed 8B store
#pragma unroll
    for (int mi = 0; mi < 4; ++mi) {
      const int rowb = m0 + wr * 64 + mi * 16 + lg * 4;
      const int b = rowb >> 11, s = rowb & 2047;
#pragma unroll
      for (int ni = 0; ni < 2; ++ni) {
        const int col = (n0 - 2048) + wc * 32 + ni * 16 + lm;
        f16x4 o;
        o[0] = (f16)acc[mi][ni][0]; o[1] = (f16)acc[mi][ni][1];
        o[2] = (f16)acc[mi][ni][2]; o[3] = (f16)acc[mi][ni][3];
        *reinterpret_cast<f16x4*>(&vtb[(size_t)(b * 1024 + col) * SEQ + s]) = o;
      }
    }
  }
}

// ---------------- output GEMM: out = att @ Wo^T + bias + resid (f32) --------
// 128x64 tile + 2-phase dbuf (r16-proven). 1D grid 512; each XCD = exactly
// one 8x8 patch of the 16x32 grid (per-XCD working set 2 MB, L2-fit).
__global__ __launch_bounds__(256) void gemm_out(const f16* __restrict__ A,
                                                const f16* __restrict__ W,
                                                float* __restrict__ out,
                                                const float* __restrict__ bias,
                                                const float* __restrict__ resid) {
  __shared__ f16 sA[2][128][64];  // 32 KB
  __shared__ f16 sB[2][64][64];   // 16 KB
  const int t = threadIdx.x, l = t & 63, w = t >> 6;
  const int wr = w >> 1, wc = w & 1, lg = l >> 4, lm = l & 15;
  const int orig = blockIdx.x;
  const int c8 = orig & 7, j = orig >> 3;
  const int by = (c8 >> 1) * 8 + (j >> 3);
  const int bxn = (c8 & 1) * 8 + (j & 7);
  const int m0 = by * 128, n0 = bxn * 64;
  const int crow = l >> 3;
  const int scol = ((l & 7) ^ crow) << 3;
  const int rsw  = (lm & 7) << 3;

  f32x4 acc[4][2] = {};

  auto stage = [&](int buf, int k0) {
#pragma unroll
    for (int cc = 0; cc < 4; ++cc) {
      const int c = w + cc * 4;
      gload16(A + (size_t)(m0 + c * 8 + crow) * DM + k0 + scol, &sA[buf][c * 8][0]);
    }
#pragma unroll
    for (int cc = 0; cc < 2; ++cc) {
      const int c = w + cc * 4;
      gload16(W + (size_t)(n0 + c * 8 + crow) * DM + k0 + scol, &sB[buf][c * 8][0]);
    }
  };

  stage(0, 0);
  __syncthreads();
  int cur = 0;

  for (int it = 0; it < DM / 64; ++it) {
    if (it < DM / 64 - 1) stage(cur ^ 1, (it + 1) * 64);
#pragma unroll
    for (int kk = 0; kk < 2; ++kk) {
      f16x8 af[4], bf[2];
#pragma unroll
      for (int i = 0; i < 4; ++i)
        af[i] = *(const f16x8*)&sA[cur][wr * 64 + i * 16 + lm][(kk * 32 + lg * 8) ^ rsw];
#pragma unroll
      for (int i = 0; i < 2; ++i)
        bf[i] = *(const f16x8*)&sB[cur][wc * 32 + i * 16 + lm][(kk * 32 + lg * 8) ^ rsw];
      __builtin_amdgcn_s_setprio(1);
#pragma unroll
      for (int mi = 0; mi < 4; ++mi)
#pragma unroll
        for (int ni = 0; ni < 2; ++ni)
          acc[mi][ni] = mfma16(af[mi], bf[ni], acc[mi][ni]);
      __builtin_amdgcn_s_setprio(0);
    }
    __syncthreads();
    cur ^= 1;
  }

#pragma unroll
  for (int mi = 0; mi < 4; ++mi) {
    const int rowb = m0 + wr * 64 + mi * 16 + lg * 4;
#pragma unroll
    for (int ni = 0; ni < 2; ++ni) {
      const int col = n0 + wc * 32 + ni * 16 + lm;
#pragma unroll
      for (int r = 0; r < 4; ++r) {
        const size_t idx = (size_t)(rowb + r) * DM + col;
        out[idx] = resid[idx] + bias[col] + acc[mi][ni][r];
      }
    }
  }
}

// ---------------- attention: swapped-QK, KEY-SPLIT (2 groups), 8 waves ------
// r19-proven exact (dbuf). Block = 512 thr = 8 waves: wq=0..3 (32 q-rows ea),
// kg=0..1. Per kg: KVBLK=64, double-buffered (64 KB LDS; grid-limited
// 2 blocks/CU). K staged ROW-PERMUTED (sigma) so swapped-QK output IS the
// PV A-fragment. No-max softmax -> key-split partials combine exactly
// (vectorized f32x4 LDS combine).
__global__ __launch_bounds__(512, 4) void attn_kernel(const f16* __restrict__ Qb,
                                                      const f16* __restrict__ Kb,
                                                      const f16* __restrict__ Vt,
                                                      f16* __restrict__ Ob) {
  __shared__ __align__(16) char smem[65536];
  // [kg][buf][row][col]
  f16 (*sK)[2][64][64] = (f16(*)[2][64][64])smem;            // 32 KB
  f16 (*sV)[2][64][64] = (f16(*)[2][64][64])(smem + 32768);  // 32 KB
  float* cb = (float*)smem;  // combine buffer (40 KB), reused after last barrier

  // XCD-locality remap (512 blocks, 512%8==0 -> bijective)
  int bx = blockIdx.x;
  bx = (bx & 7) * 64 + (bx >> 3);
  const int qt = bx & 15, bh = bx >> 4;    // qt: 16 tiles of 128 q-rows
  const int h = bh & 15, b = bh >> 4;
  const int t = threadIdx.x, l = t & 63, w = t >> 6;
  const int kg = w >> 2, wq = w & 3;
  const int lg = l >> 4, lm = l & 15;
  const float K2 = 0.18033688f;  // (1/sqrt(64)) * log2(e)

  // Q frags (B operand) for 2 q-groups; rows = qt*128 + wq*32 + qg*16 + lm
  f16x8 qf[2][2];
#pragma unroll
  for (int qg = 0; qg < 2; ++qg) {
    const f16* qptr =
        Qb + (size_t)(b * SEQ + qt * 128 + wq * 32 + qg * 16 + lm) * DM + h * DKH;
    qf[qg][0] = *(const f16x8*)(qptr + lg * 8);
    qf[qg][1] = *(const f16x8*)(qptr + 32 + lg * 8);
#pragma unroll
    for (int j = 0; j < 8; ++j) {
      qf[qg][0][j] = (f16)((float)qf[qg][0][j] * K2);
      qf[qg][1][j] = (f16)((float)qf[qg][1][j] * K2);
    }
  }

  const f16x8 ones = {(f16)1, (f16)1, (f16)1, (f16)1,
                      (f16)1, (f16)1, (f16)1, (f16)1};

  f32x4 oacc[2][4] = {};
  f32x4 oden[2] = {};

  const int crow = l >> 3;                 // lane's row within 8-row chunk
  const int scol = ((l & 7) ^ crow) << 3;  // pre-swizzled source col (f16)
  const int rsw  = (lm & 7) << 3;          // read-side swizzle XOR (f16)

  // Hoisted staging pointers: 2 K-chunks + 2 V-chunks per wave per 64-key tile
  const f16* kptr[2];
  const f16* vptr[2];
#pragma unroll
  for (int cc = 0; cc < 2; ++cc) {
    const int c = wq + cc * 4;             // chunk 0..7 (8 rows each)
    const int krow = c * 8 + crow;         // 0..63
    // sigma(krow): (nf,lg,r) bits -> key = (nf>>1)*32 + lg*8 + (nf&1)*4 + r
    const int nfp = krow >> 4, lgp = (krow >> 2) & 3, rp = krow & 3;
    const int key = (nfp >> 1) * 32 + lgp * 8 + (nfp & 1) * 4 + rp;
    kptr[cc] = Kb + (size_t)(b * SEQ + kg * 1024 + key) * DM + h * DKH + scol;
    vptr[cc] = Vt + (size_t)(bh * DKH + c * 8 + crow) * SEQ + kg * 1024 + scol;
  }

  auto stage = [&](int buf) {
#pragma unroll
    for (int cc = 0; cc < 2; ++cc) {
      const int c = wq + cc * 4;
      gload16(kptr[cc], &sK[kg][buf][c * 8][0]);
      gload16(vptr[cc], &sV[kg][buf][c * 8][0]);
      kptr[cc] += 64 * DM;
      vptr[cc] += 64;
    }
  };

  stage(0);
  __syncthreads();
  int cur = 0;

  union PU { f16x8 v; f16x2 hh[4]; };

  for (int kt = 0; kt < 16; ++kt) {        // 16 x 64-key tiles per key-group
    if (kt < 15) stage(cur ^ 1);

    // swapped QK^T: D[key][q]; kf shared across both q-groups
    f32x4 sc[2][4] = {};
    __builtin_amdgcn_s_setprio(1);
#pragma unroll
    for (int kk = 0; kk < 2; ++kk)
#pragma unroll
      for (int nf = 0; nf < 4; ++nf) {
        f16x8 kf = *(const f16x8*)
            &sK[kg][cur][nf * 16 + lm][(kk * 32 + lg * 8) ^ rsw];
        sc[0][nf] = mfma16(kf, qf[0][kk], sc[0][nf]);
        sc[1][nf] = mfma16(kf, qf[1][kk], sc[1][nf]);
      }
    __builtin_amdgcn_s_setprio(0);

    // P = exp2(s), packed pairwise straight into PV A-fragments
    PU pu[2][2];
#pragma unroll
    for (int qg = 0; qg < 2; ++qg)
#pragma unroll
      for (int nf = 0; nf < 4; ++nf) {
        float e0 = __builtin_amdgcn_exp2f(sc[qg][nf][0]);
        float e1 = __builtin_amdgcn_exp2f(sc[qg][nf][1]);
        float e2 = __builtin_amdgcn_exp2f(sc[qg][nf][2]);
        float e3 = __builtin_amdgcn_exp2f(sc[qg][nf][3]);
        pu[qg][nf >> 1].hh[(nf & 1) * 2 + 0] = cvt_pk(e0, e1);
        pu[qg][nf >> 1].hh[(nf & 1) * 2 + 1] = cvt_pk(e2, e3);
      }

    // PV (+den)
    __builtin_amdgcn_s_setprio(1);
#pragma unroll
    for (int ks = 0; ks < 2; ++ks) {
#pragma unroll
      for (int ni = 0; ni < 4; ++ni) {
        f16x8 vf = *(const f16x8*)
            &sV[kg][cur][ni * 16 + lm][(ks * 32 + lg * 8) ^ rsw];
        oacc[0][ni] = mfma16(pu[0][ks].v, vf, oacc[0][ni]);
        oacc[1][ni] = mfma16(pu[1][ks].v, vf, oacc[1][ni]);
      }
      oden[0] = mfma16(pu[0][ks].v, ones, oden[0]);
      oden[1] = mfma16(pu[1][ks].v, ones, oden[1]);
    }
    __builtin_amdgcn_s_setprio(0);

    __syncthreads();   // also guards smem reuse as combine buffer after loop
    cur ^= 1;
  }

  // ---- key-group combine (vectorized): kg=1 dumps, kg=0 adds + writes ------
  float* myp = cb + (size_t)(wq * 64 + l) * 40;  // 160B stride, 16B aligned
  if (kg == 1) {
#pragma unroll
    for (int qg = 0; qg < 2; ++qg)
#pragma unroll
      for (int ni = 0; ni < 4; ++ni)
        *reinterpret_cast<f32x4*>(myp + qg * 16 + ni * 4) = oacc[qg][ni];
#pragma unroll
    for (int qg = 0; qg < 2; ++qg)
      *reinterpret_cast<f32x4*>(myp + 32 + qg * 4) = oden[qg];
  }
  __syncthreads();
  if (kg == 0) {
#pragma unroll
    for (int qg = 0; qg < 2; ++qg) {
#pragma unroll
      for (int ni = 0; ni < 4; ++ni)
        oacc[qg][ni] += *reinterpret_cast<const f32x4*>(myp + qg * 16 + ni * 4);
      f32x4 od = *reinterpret_cast<const f32x4*>(myp + 32 + qg * 4);
      float rd[4];
#pragma unroll
      for (int r = 0; r < 4; ++r) rd[r] = 1.f / (oden[qg][r] + od[r]);
#pragma unroll
      for (int ni = 0; ni < 4; ++ni)
#pragma unroll
        for (int r = 0; r < 4; ++r) {
          const int q = qt * 128 + wq * 32 + qg * 16 + lg * 4 + r;
          const int d = ni * 16 + lm;
          Ob[(size_t)(b * SEQ + q) * DM + h * DKH + d] =
              (f16)(oacc[qg][ni][r] * rd[r]);
        }
    }
  }
}

// ---------------- launch ----------------
extern "C" void kernel_launch(void* const* d_in, const int* in_sizes, int n_in,
                              void* d_out, int out_size, void* d_ws, size_t ws_size,
                              hipStream_t stream) {
  const float* x   = (const float*)d_in[0];
  const float* w_q = (const float*)d_in[1];
  const float* w_k = (const float*)d_in[2];
  const float* w_v = (const float*)d_in[3];
  const float* w_o = (const float*)d_in[4];
  const float* b_o = (const float*)d_in[5];
  const float* lng = (const float*)d_in[6];
  const float* lnb = (const float*)d_in[7];
  float* out = (float*)d_out;

  char* ws = (char*)d_ws;
  const size_t MB = 1ull << 20;
  f16* xn   = (f16*)(ws + 0 * MB);   // 8 MB
  f16* wqkv = (f16*)(ws + 8 * MB);   // 6 MB [3072][1024] (+2 MB wo, contiguous)
  f16* woh  = (f16*)(ws + 14 * MB);  // 2 MB
  f16* qb   = (f16*)(ws + 16 * MB);  // 8 MB
  f16* kb   = (f16*)(ws + 24 * MB);  // 8 MB
  f16* vtb  = (f16*)(ws + 32 * MB);  // 8 MB
  f16* att  = (f16*)(ws + 40 * MB);  // 8 MB

  prep_kernel<<<8192, 256, 0, stream>>>(x, w_q, w_k, w_v, w_o, lng, lnb, wqkv, xn);
  gemm_qkv<<<1536, 256, 0, stream>>>(xn, wqkv, qb, kb, vtb);
  attn_kernel<<<512, 512, 0, stream>>>(qb, kb, vtb, att);
  gemm_out<<<512, 256, 0, stream>>>(att, woh, out, b_o, x);
}